// Round 1
// baseline (440.922 us; speedup 1.0000x reference)
//
#include <hip/hip_runtime.h>

#define N_NODES 10000
#define N_EDGES 160000
#define MAXT     19400              // >= sum(ceil(deg/16)) <= (E + 15N)/16 = 19375
#define NSLOT    (MAXT * 16 + 16)   // 16-aligned CSR slots + guard
#define MSG_GRID 5000               // x4 strided tiles = 20000 slots
#define RC_BLOCKS 5000              // E*8 / 256
#define PAD_BLOCKS 625              // N*16 / 256

typedef __attribute__((ext_vector_type(8))) __bf16 bf16x8;
typedef __attribute__((ext_vector_type(8))) unsigned short u16x8;
typedef __attribute__((ext_vector_type(4))) float f32x4;

static __device__ __forceinline__ unsigned short f2bf(float x) {
    union { float f; unsigned u; } un;
    un.f = x;
    unsigned r = un.u + 0x7fffu + ((un.u >> 16) & 1u);  // RNE
    return (unsigned short)(r >> 16);
}

static __device__ __forceinline__ float bf2f(unsigned short h) {
    union { unsigned u; float f; } un;
    un.u = ((unsigned)h) << 16;
    return un.f;
}

// ---------------------------------------------------------------------------
// Fused init: weight transpose->bf16, out0=s / out1=v, vbf2 packing,
// degree histogram. Grid covers N*384 = 3.84M threads.
// ---------------------------------------------------------------------------
__global__ __launch_bounds__(256) void init_kernel(
    const float* __restrict__ s, const float* __restrict__ v,
    const int* __restrict__ eix,
    const float* __restrict__ W1, const float* __restrict__ W2,
    const float* __restrict__ Wr,
    float* __restrict__ out0, float* __restrict__ out1,
    unsigned short* __restrict__ vbf2, int* __restrict__ cnt,
    unsigned short* __restrict__ W1T, unsigned short* __restrict__ W2T,
    unsigned short* __restrict__ WrT)
{
    int tid = blockIdx.x * 256 + threadIdx.x;
    if (tid < N_NODES * 384) out1[tid] = v[tid];
    if (tid < N_NODES * 128) {
        out0[tid] = s[tid];
        int n = tid >> 7, f = tid & 127;
        ushort4 q;
        q.x = f2bf(v[(size_t)n * 384 + f]);
        q.y = f2bf(v[(size_t)n * 384 + 128 + f]);
        q.z = f2bf(v[(size_t)n * 384 + 256 + f]);
        q.w = 0;
        *reinterpret_cast<ushort4*>(vbf2 + (size_t)tid * 4) = q;
    }
    if (tid < 131072) {                          // W2T [1024][128]
        int n = tid >> 7, k = tid & 127;
        W2T[tid] = f2bf(W2[k * 1024 + n]);
    }
    if (tid < 16384) {                           // W1T [128][128]
        int n = tid >> 7, k = tid & 127;
        W1T[tid] = f2bf(W1[k * 128 + n]);
    }
    if (tid < 32768) {                           // WrT [1024][32]
        int n = tid >> 5, k = tid & 31;
        WrT[tid] = f2bf(Wr[k * 1024 + n]);
    }
    if (tid < N_EDGES) atomicAdd(&cnt[eix[tid]], 1);
}

// ---------------------------------------------------------------------------
// Exclusive scan over tile counts; emits 16-aligned slot bases (nb/cursor in
// SLOT units) and the tile->node worklist.
// ---------------------------------------------------------------------------
__global__ __launch_bounds__(1024) void scan_kernel(
    const int* __restrict__ cnt, int* __restrict__ cursor,
    int* __restrict__ nb, int* __restrict__ tile_node,
    int* __restrict__ ntiles)
{
    __shared__ int ws[16];
    __shared__ int run_s;
    int t = threadIdx.x, lane = t & 63, wid = t >> 6;
    if (t == 0) run_s = 0;
    __syncthreads();
    for (int base = 0; base < N_NODES; base += 1024) {
        int idx = base + t;
        int deg = (idx < N_NODES) ? cnt[idx] : 0;
        int tc = (deg + 15) >> 4;
        int x = tc;
        #pragma unroll
        for (int o = 1; o < 64; o <<= 1) {
            int y = __shfl_up(x, o);
            if (lane >= o) x += y;
        }
        if (lane == 63) ws[wid] = x;
        __syncthreads();
        if (wid == 0) {
            int wv = (lane < 16) ? ws[lane] : 0;
            #pragma unroll
            for (int o = 1; o < 16; o <<= 1) {
                int y = __shfl_up(wv, o);
                if (lane >= o) wv += y;
            }
            if (lane < 16) ws[lane] = wv;
        }
        __syncthreads();
        int wb = wid ? ws[wid - 1] : 0;
        int ex = run_s + wb + x - tc;            // exclusive scan, tile units
        if (idx < N_NODES) {
            nb[idx] = ex * 16;                    // immutable slot base
            cursor[idx] = ex * 16;                // working cursor for rc
            for (int k = 0; k < tc; ++k) tile_node[ex + k] = idx;
        }
        __syncthreads();
        if (t == 0) run_s += ws[15];
        __syncthreads();
    }
    if (t == 0) *ntiles = run_s;
}

// ---------------------------------------------------------------------------
// rc part (blocks < RC_BLOCKS): per edge, Rc = bf16(R1*f1+R2*f2+R3*f3) and a
// 64B packed header {j, fsum, u1, u2, u3}, both written at the CSR slot so
// msg_kernel reads them CONTIGUOUSLY (no elist indirection).
// pad part (blocks >= RC_BLOCKS): zero the <=15 pad slots per node so msg
// needs no masking at all.
// ---------------------------------------------------------------------------
__global__ __launch_bounds__(256) void rc_pad_kernel(
    const float* __restrict__ R1, const float* __restrict__ R2,
    const float* __restrict__ R3,
    const float* __restrict__ f1, const float* __restrict__ f2,
    const float* __restrict__ f3,
    const float* __restrict__ u1, const float* __restrict__ u2,
    const float* __restrict__ u3,
    const int* __restrict__ eix, const int* __restrict__ cnt,
    const int* __restrict__ nb, int* __restrict__ cursor,
    unsigned short* __restrict__ Rc_s, float* __restrict__ hdr)
{
    if (blockIdx.x >= RC_BLOCKS) {
        int t2 = (blockIdx.x - RC_BLOCKS) * 256 + threadIdx.x;   // [0, 16N)
        int n = t2 >> 4, r = t2 & 15;
        int deg = cnt[n], tc = (deg + 15) >> 4;
        int p = deg + r;
        if (p < tc * 16) {
            size_t slot = (size_t)nb[n] + p;
            f32x4 z = {0.f, 0.f, 0.f, 0.f};
            f32x4* hp = reinterpret_cast<f32x4*>(hdr + slot * 16);
            hp[0] = z; hp[1] = z; hp[2] = z; hp[3] = z;
            f32x4* rp = reinterpret_cast<f32x4*>(Rc_s + slot * 32);
            rp[0] = z; rp[1] = z; rp[2] = z; rp[3] = z;
        }
        return;
    }
    int tid = blockIdx.x * 256 + threadIdx.x;    // exactly E*8 threads
    int e = tid >> 3, sub = tid & 7;
    int lane = threadIdx.x & 63;
    float a = f1[e], b = f2[e], c = f3[e];
    int k0 = sub * 4;
    float4 r1 = *reinterpret_cast<const float4*>(R1 + (size_t)e * 32 + k0);
    float4 r2 = *reinterpret_cast<const float4*>(R2 + (size_t)e * 32 + k0);
    float4 r3 = *reinterpret_cast<const float4*>(R3 + (size_t)e * 32 + k0);
    ushort4 o;
    o.x = f2bf(r1.x * a + r2.x * b + r3.x * c);
    o.y = f2bf(r1.y * a + r2.y * b + r3.y * c);
    o.z = f2bf(r1.z * a + r2.z * b + r3.z * c);
    o.w = f2bf(r1.w * a + r2.w * b + r3.w * c);
    int slot = 0;
    if (sub == 0) slot = atomicAdd(&cursor[eix[e]], 1);
    slot = __shfl(slot, lane & 56);              // broadcast from sub0
    *reinterpret_cast<ushort4*>(Rc_s + (size_t)slot * 32 + k0) = o;
    if (sub == 0) {
        float4 h;
        h.x = __int_as_float(eix[N_EDGES + e]);  // j
        h.y = a + b + c;                         // fsum
        h.z = 0.f; h.w = 0.f;
        *reinterpret_cast<float4*>(hdr + (size_t)slot * 16) = h;
    } else if (sub < 4) {
        const float* up = (sub == 1 ? u1 : (sub == 2 ? u2 : u3)) + (size_t)e * 3;
        float4 h;
        h.x = up[0]; h.y = up[1]; h.z = up[2]; h.w = 0.f;
        *reinterpret_cast<float4*>(hdr + (size_t)slot * 16 + (size_t)sub * 4) = h;
    }
}

// ---------------------------------------------------------------------------
// phi = silu(s@W1 + b1) @ W2 + b2, stored CHUNK-MINOR: phi2[n][f][c] bf16.
// ---------------------------------------------------------------------------
__global__ __launch_bounds__(256) void phi_kernel(
    const float* __restrict__ s, const unsigned short* __restrict__ W1T,
    const float* __restrict__ b1, const unsigned short* __restrict__ W2T,
    const float* __restrict__ b2, unsigned short* __restrict__ phi2)
{
    __shared__ unsigned short h_lds[64][136];
    int t = threadIdx.x, lane = t & 63, w = t >> 6;
    int quad = lane >> 4, l16 = lane & 15;
    int m0 = (blockIdx.x >> 2) * 64;
    int colg = blockIdx.x & 3;

    int arow = m0 + w * 16 + l16;
    if (arow > N_NODES - 1) arow = N_NODES - 1;
    bf16x8 afr[4];
    #pragma unroll
    for (int ks = 0; ks < 4; ++ks) {
        const float* sp = s + (size_t)arow * 128 + ks * 32 + quad * 8;
        #pragma unroll
        for (int jj = 0; jj < 8; ++jj) afr[ks][jj] = (__bf16)sp[jj];
    }
    #pragma unroll
    for (int cg = 0; cg < 8; ++cg) {
        int col = cg * 16 + l16;
        f32x4 acc = {0.f, 0.f, 0.f, 0.f};
        #pragma unroll
        for (int ks = 0; ks < 4; ++ks) {
            bf16x8 bf = *reinterpret_cast<const bf16x8*>(W1T + (size_t)col * 128 + ks * 32 + quad * 8);
            acc = __builtin_amdgcn_mfma_f32_16x16x32_bf16(afr[ks], bf, acc, 0, 0, 0);
        }
        float bb = b1[col];
        #pragma unroll
        for (int r = 0; r < 4; ++r) {
            int row = w * 16 + quad * 4 + r;
            float val = acc[r] + bb;
            h_lds[row][col] = f2bf(val / (1.f + __expf(-val)));
        }
    }
    __syncthreads();

    bf16x8 a2[4][4];
    #pragma unroll
    for (int rg = 0; rg < 4; ++rg)
        #pragma unroll
        for (int ks = 0; ks < 4; ++ks)
            a2[rg][ks] = *reinterpret_cast<const bf16x8*>(&h_lds[rg * 16 + l16][ks * 32 + quad * 8]);
    #pragma unroll
    for (int i = 0; i < 4; ++i) {
        int col = colg * 256 + w * 64 + i * 16 + l16;
        f32x4 acc2[4] = {{0,0,0,0},{0,0,0,0},{0,0,0,0},{0,0,0,0}};
        #pragma unroll
        for (int ks = 0; ks < 4; ++ks) {
            bf16x8 bf = *reinterpret_cast<const bf16x8*>(W2T + (size_t)col * 128 + ks * 32 + quad * 8);
            #pragma unroll
            for (int rg = 0; rg < 4; ++rg)
                acc2[rg] = __builtin_amdgcn_mfma_f32_16x16x32_bf16(a2[rg][ks], bf, acc2[rg], 0, 0, 0);
        }
        float bb = b2[col];
        int f = col & 127, cc = col >> 7;
        #pragma unroll
        for (int rg = 0; rg < 4; ++rg)
            #pragma unroll
            for (int r = 0; r < 4; ++r) {
                int row = m0 + rg * 16 + quad * 4 + r;
                if (row < N_NODES)
                    phi2[(size_t)row * 1024 + f * 8 + cc] = f2bf(acc2[rg][r] + bb);
            }
    }
}

// ---------------------------------------------------------------------------
// Main msg kernel: barrier-free, LDS-free. All per-tile inputs (Rc, header)
// are slot-contiguous; pad slots are pre-zeroed so no masking is needed.
// Only the j->phi2/vbf2 gather is scattered; js are prefetched for all 4 rows
// before the dependent loads.
// ---------------------------------------------------------------------------
__global__ __launch_bounds__(512) void msg_kernel(
    const unsigned short* __restrict__ Rc_s, const float* __restrict__ hdr,
    const unsigned short* __restrict__ phi2, const unsigned short* __restrict__ vbf2,
    const unsigned short* __restrict__ WrT, const float* __restrict__ br,
    const int* __restrict__ tile_node, const int* __restrict__ ntiles,
    float* __restrict__ out0, float* __restrict__ out1)
{
    int t = threadIdx.x, lane = t & 63, w = t >> 6;
    int quad = lane >> 4, l16 = lane & 15;
    int fcol = w * 16 + l16;
    const int nt = *ntiles;

    bf16x8 bfrag[8];
    float brv[8];
    #pragma unroll
    for (int c = 0; c < 8; ++c) {
        int col = c * 128 + fcol;
        bfrag[c] = *reinterpret_cast<const bf16x8*>(WrT + (size_t)col * 32 + quad * 8);
        brv[c] = br[col];
    }

    for (int t4 = 0; t4 < 4; ++t4) {
        int tile = blockIdx.x + t4 * MSG_GRID;
        if (tile >= nt) break;                   // uniform across block
        int node = tile_node[tile];
        size_t s0 = (size_t)tile * 16;

        // A-fragment: contiguous 1KB per tile (pad rows are zero)
        bf16x8 af = *reinterpret_cast<const bf16x8*>(Rc_s + (s0 + l16) * 32 + quad * 8);
        f32x4 acc[8];
        #pragma unroll
        for (int c = 0; c < 8; ++c) {
            f32x4 z = {0.f, 0.f, 0.f, 0.f};
            acc[c] = __builtin_amdgcn_mfma_f32_16x16x32_bf16(af, bfrag[c], z, 0, 0, 0);
        }

        // prefetch j/fsum for all 4 rows, then issue the dependent gathers wide
        int jj[4]; float fsv[4];
        #pragma unroll
        for (int r = 0; r < 4; ++r) {
            size_t slot = s0 + (quad * 4 + r);
            float2 h0 = *reinterpret_cast<const float2*>(hdr + slot * 16);
            jj[r] = __float_as_int(h0.x);
            fsv[r] = h0.y;
        }

        float ds = 0.f, d0 = 0.f, d1 = 0.f, d2 = 0.f;
        #pragma unroll
        for (int r = 0; r < 4; ++r) {
            size_t slot = s0 + (quad * 4 + r);
            const f32x4* hp = reinterpret_cast<const f32x4*>(hdr + slot * 16);
            size_t o = (size_t)jj[r] * 128 + fcol;
            u16x8 ph = *reinterpret_cast<const u16x8*>(phi2 + o * 8);
            ushort4 vb = *reinterpret_cast<const ushort4*>(vbf2 + o * 4);
            f32x4 U1 = hp[1], U2 = hp[2], U3 = hp[3];
            float fs = fsv[r];
            float x[8];
            #pragma unroll
            for (int c = 0; c < 8; ++c)
                x[c] = bf2f(ph[c]) * (acc[c][r] + brv[c] * fs);
            float vjx = bf2f(vb.x), vjy = bf2f(vb.y), vjz = bf2f(vb.z);
            // d += x1*vj + x2*u1 + x3*u2 + x4*u3 + vj x (x5*u1 + x6*u2 + x7*u3)
            float qx = x[5] * U1.x + x[6] * U2.x + x[7] * U3.x;
            float qy = x[5] * U1.y + x[6] * U2.y + x[7] * U3.y;
            float qz = x[5] * U1.z + x[6] * U2.z + x[7] * U3.z;
            ds += x[0];
            d0 += x[1] * vjx + x[2] * U1.x + x[3] * U2.x + x[4] * U3.x + vjy * qz - vjz * qy;
            d1 += x[1] * vjy + x[2] * U1.y + x[3] * U2.y + x[4] * U3.y + vjz * qx - vjx * qz;
            d2 += x[1] * vjz + x[2] * U1.z + x[3] * U2.z + x[4] * U3.z + vjx * qy - vjy * qx;
        }

        ds += __shfl_xor(ds, 16); ds += __shfl_xor(ds, 32);
        d0 += __shfl_xor(d0, 16); d0 += __shfl_xor(d0, 32);
        d1 += __shfl_xor(d1, 16); d1 += __shfl_xor(d1, 32);
        d2 += __shfl_xor(d2, 16); d2 += __shfl_xor(d2, 32);

        if (quad == 0) {
            atomicAdd(&out0[(size_t)node * 128 + fcol], ds);
            size_t vo = (size_t)node * 384 + fcol;
            atomicAdd(&out1[vo], d0);
            atomicAdd(&out1[vo + 128], d1);
            atomicAdd(&out1[vo + 256], d2);
        }
    }
}

// ---------------------------------------------------------------------------
extern "C" void kernel_launch(void* const* d_in, const int* in_sizes, int n_in,
                              void* d_out, int out_size, void* d_ws, size_t ws_size,
                              hipStream_t stream) {
    const float* s  = (const float*)d_in[0];
    const float* v  = (const float*)d_in[1];
    const float* R1 = (const float*)d_in[2];
    const float* R2 = (const float*)d_in[3];
    const float* R3 = (const float*)d_in[4];
    const float* f1 = (const float*)d_in[5];
    const float* f2 = (const float*)d_in[6];
    const float* f3 = (const float*)d_in[7];
    const float* u1 = (const float*)d_in[8];
    const float* u2 = (const float*)d_in[9];
    const float* u3 = (const float*)d_in[10];
    const int*  eix = (const int*)d_in[11];
    const float* W1 = (const float*)d_in[12];
    const float* b1 = (const float*)d_in[13];
    const float* W2 = (const float*)d_in[14];
    const float* b2 = (const float*)d_in[15];
    const float* Wr = (const float*)d_in[16];
    const float* br = (const float*)d_in[17];

    char* ws = (char*)d_ws;
    size_t off = 0;
    auto alloc = [&](size_t bytes) -> void* {
        void* p = ws + off;
        off = (off + bytes + 255) & ~(size_t)255;
        return p;
    };
    int* cnt       = (int*)alloc((size_t)N_NODES * 4);
    int* cursor    = (int*)alloc((size_t)N_NODES * 4);
    int* nb        = (int*)alloc((size_t)N_NODES * 4);
    int* tile_node = (int*)alloc((size_t)MAXT * 4);
    int* ntiles    = (int*)alloc(4);
    unsigned short* Rc_s = (unsigned short*)alloc((size_t)NSLOT * 32 * 2);
    float* hdr           = (float*)alloc((size_t)NSLOT * 16 * 4);
    unsigned short* vbf2 = (unsigned short*)alloc((size_t)N_NODES * 128 * 4 * 2);
    unsigned short* phi2 = (unsigned short*)alloc((size_t)N_NODES * 1024 * 2);
    unsigned short* W1T  = (unsigned short*)alloc(128 * 128 * 2);
    unsigned short* W2T  = (unsigned short*)alloc(1024 * 128 * 2);
    unsigned short* WrT  = (unsigned short*)alloc(1024 * 32 * 2);
    (void)ws_size; (void)in_sizes; (void)n_in; (void)out_size;

    float* out0 = (float*)d_out;
    float* out1 = out0 + (size_t)N_NODES * 128;

    hipMemsetAsync(cnt, 0, (size_t)N_NODES * 4, stream);
    init_kernel<<<15000, 256, 0, stream>>>(s, v, eix, W1, W2, Wr,
                                           out0, out1, vbf2, cnt, W1T, W2T, WrT);
    scan_kernel<<<1, 1024, 0, stream>>>(cnt, cursor, nb, tile_node, ntiles);
    rc_pad_kernel<<<RC_BLOCKS + PAD_BLOCKS, 256, 0, stream>>>(
        R1, R2, R3, f1, f2, f3, u1, u2, u3, eix, cnt, nb, cursor, Rc_s, hdr);
    phi_kernel<<<628, 256, 0, stream>>>(s, W1T, b1, W2T, b2, phi2);
    msg_kernel<<<MSG_GRID, 512, 0, stream>>>(Rc_s, hdr, phi2, vbf2, WrT, br,
                                             tile_node, ntiles, out0, out1);
}

// Round 2
// 360.272 us; speedup vs baseline: 1.2239x; 1.2239x over previous
//
#include <hip/hip_runtime.h>

#define N_NODES 10000
#define N_EDGES 160000
#define MAXT     19400              // >= sum(ceil(deg/16)) <= (E + 15N)/16 = 19375
#define NSLOT    (MAXT * 16 + 16)   // 16-aligned CSR slots + guard
#define MSG_GRID 5000               // x4 strided tiles = 20000 slots
#define PHI_BLOCKS 628
#define RC_BLOCKS 5000              // E*8 / 256
#define PAD_BLOCKS 625              // N*16 / 256

typedef __attribute__((ext_vector_type(8))) __bf16 bf16x8;
typedef __attribute__((ext_vector_type(8))) unsigned short u16x8;
typedef __attribute__((ext_vector_type(4))) float f32x4;

static __device__ __forceinline__ unsigned short f2bf(float x) {
    union { float f; unsigned u; } un;
    un.f = x;
    unsigned r = un.u + 0x7fffu + ((un.u >> 16) & 1u);  // RNE
    return (unsigned short)(r >> 16);
}

static __device__ __forceinline__ float bf2f(unsigned short h) {
    union { unsigned u; float f; } un;
    un.u = ((unsigned)h) << 16;
    return un.f;
}

// ---------------------------------------------------------------------------
// Fused init: float4 copies, weight transpose->bf16, vbf2 packing, degree
// histogram. Grid = 5000x256 = 1.28M threads (largest range).
// ---------------------------------------------------------------------------
__global__ __launch_bounds__(256) void init_kernel(
    const float* __restrict__ s, const float* __restrict__ v,
    const int* __restrict__ eix,
    const float* __restrict__ W1, const float* __restrict__ W2,
    const float* __restrict__ Wr,
    float* __restrict__ out0, float* __restrict__ out1,
    unsigned short* __restrict__ vbf2, int* __restrict__ cnt,
    unsigned short* __restrict__ W1T, unsigned short* __restrict__ W2T,
    unsigned short* __restrict__ WrT)
{
    int tid = blockIdx.x * 256 + threadIdx.x;
    if (tid < N_NODES * 96)                      // out1 = v, float4
        reinterpret_cast<float4*>(out1)[tid] = reinterpret_cast<const float4*>(v)[tid];
    if (tid < N_NODES * 32)                      // out0 = s, float4
        reinterpret_cast<float4*>(out0)[tid] = reinterpret_cast<const float4*>(s)[tid];
    if (tid < N_NODES * 128) {                   // vbf2[n][f] = {vx,vy,vz,0} bf16
        int n = tid >> 7, f = tid & 127;
        ushort4 q;
        q.x = f2bf(v[(size_t)n * 384 + f]);
        q.y = f2bf(v[(size_t)n * 384 + 128 + f]);
        q.z = f2bf(v[(size_t)n * 384 + 256 + f]);
        q.w = 0;
        *reinterpret_cast<ushort4*>(vbf2 + (size_t)tid * 4) = q;
    }
    if (tid < 131072) {                          // W2T [1024][128]
        int n = tid >> 7, k = tid & 127;
        W2T[tid] = f2bf(W2[k * 1024 + n]);
    }
    if (tid < 16384) {                           // W1T [128][128]
        int n = tid >> 7, k = tid & 127;
        W1T[tid] = f2bf(W1[k * 128 + n]);
    }
    if (tid < 32768) {                           // WrT [1024][32]
        int n = tid >> 5, k = tid & 31;
        WrT[tid] = f2bf(Wr[k * 1024 + n]);
    }
    if (tid < N_EDGES) atomicAdd(&cnt[eix[tid]], 1);
}

// ---------------------------------------------------------------------------
// Exclusive scan over tile counts; emits 16-aligned slot bases (nb/cursor in
// SLOT units) and the tile->node worklist.
// ---------------------------------------------------------------------------
__global__ __launch_bounds__(1024) void scan_kernel(
    const int* __restrict__ cnt, int* __restrict__ cursor,
    int* __restrict__ nb, int* __restrict__ tile_node,
    int* __restrict__ ntiles)
{
    __shared__ int ws[16];
    __shared__ int run_s;
    int t = threadIdx.x, lane = t & 63, wid = t >> 6;
    if (t == 0) run_s = 0;
    __syncthreads();
    for (int base = 0; base < N_NODES; base += 1024) {
        int idx = base + t;
        int deg = (idx < N_NODES) ? cnt[idx] : 0;
        int tc = (deg + 15) >> 4;
        int x = tc;
        #pragma unroll
        for (int o = 1; o < 64; o <<= 1) {
            int y = __shfl_up(x, o);
            if (lane >= o) x += y;
        }
        if (lane == 63) ws[wid] = x;
        __syncthreads();
        if (wid == 0) {
            int wv = (lane < 16) ? ws[lane] : 0;
            #pragma unroll
            for (int o = 1; o < 16; o <<= 1) {
                int y = __shfl_up(wv, o);
                if (lane >= o) wv += y;
            }
            if (lane < 16) ws[lane] = wv;
        }
        __syncthreads();
        int wb = wid ? ws[wid - 1] : 0;
        int ex = run_s + wb + x - tc;            // exclusive scan, tile units
        if (idx < N_NODES) {
            nb[idx] = ex * 16;                    // immutable slot base
            cursor[idx] = ex * 16;                // working cursor for rc
            for (int k = 0; k < tc; ++k) tile_node[ex + k] = idx;
        }
        __syncthreads();
        if (t == 0) run_s += ws[15];
        __syncthreads();
    }
    if (t == 0) *ntiles = run_s;
}

// ---------------------------------------------------------------------------
// Fused rc + pad + phi (one launch -> memory-bound rc overlaps MFMA-bound phi).
//  blocks [0, PHI_BLOCKS):                 phi = silu(s@W1+b1)@W2+b2 -> phi2
//  blocks [PHI_BLOCKS, +RC_BLOCKS):        per-edge Rc/hdr at CSR slot
//  blocks [PHI_BLOCKS+RC_BLOCKS, +PAD):    zero pad slots
// ---------------------------------------------------------------------------
__global__ __launch_bounds__(256) void rc_phi_kernel(
    const float* __restrict__ R1, const float* __restrict__ R2,
    const float* __restrict__ R3,
    const float* __restrict__ f1, const float* __restrict__ f2,
    const float* __restrict__ f3,
    const float* __restrict__ u1, const float* __restrict__ u2,
    const float* __restrict__ u3,
    const int* __restrict__ eix, const int* __restrict__ cnt,
    const int* __restrict__ nb, int* __restrict__ cursor,
    unsigned short* __restrict__ Rc_s, float* __restrict__ hdr,
    const float* __restrict__ s, const unsigned short* __restrict__ W1T,
    const float* __restrict__ b1, const unsigned short* __restrict__ W2T,
    const float* __restrict__ b2, unsigned short* __restrict__ phi2)
{
    __shared__ unsigned short h_lds[64][136];
    int bx = blockIdx.x;

    if (bx < PHI_BLOCKS) {
        // ---------------- phi ----------------
        int t = threadIdx.x, lane = t & 63, w = t >> 6;
        int quad = lane >> 4, l16 = lane & 15;
        int m0 = (bx >> 2) * 64;
        int colg = bx & 3;

        int arow = m0 + w * 16 + l16;
        if (arow > N_NODES - 1) arow = N_NODES - 1;
        bf16x8 afr[4];
        #pragma unroll
        for (int ks = 0; ks < 4; ++ks) {
            const float* sp = s + (size_t)arow * 128 + ks * 32 + quad * 8;
            #pragma unroll
            for (int jj = 0; jj < 8; ++jj) afr[ks][jj] = (__bf16)sp[jj];
        }
        #pragma unroll
        for (int cg = 0; cg < 8; ++cg) {
            int col = cg * 16 + l16;
            f32x4 acc = {0.f, 0.f, 0.f, 0.f};
            #pragma unroll
            for (int ks = 0; ks < 4; ++ks) {
                bf16x8 bf = *reinterpret_cast<const bf16x8*>(W1T + (size_t)col * 128 + ks * 32 + quad * 8);
                acc = __builtin_amdgcn_mfma_f32_16x16x32_bf16(afr[ks], bf, acc, 0, 0, 0);
            }
            float bb = b1[col];
            #pragma unroll
            for (int r = 0; r < 4; ++r) {
                int row = w * 16 + quad * 4 + r;
                float val = acc[r] + bb;
                h_lds[row][col] = f2bf(val / (1.f + __expf(-val)));
            }
        }
        __syncthreads();

        bf16x8 a2[4][4];
        #pragma unroll
        for (int rg = 0; rg < 4; ++rg)
            #pragma unroll
            for (int ks = 0; ks < 4; ++ks)
                a2[rg][ks] = *reinterpret_cast<const bf16x8*>(&h_lds[rg * 16 + l16][ks * 32 + quad * 8]);
        #pragma unroll
        for (int i = 0; i < 4; ++i) {
            int col = colg * 256 + w * 64 + i * 16 + l16;
            f32x4 acc2[4] = {{0,0,0,0},{0,0,0,0},{0,0,0,0},{0,0,0,0}};
            #pragma unroll
            for (int ks = 0; ks < 4; ++ks) {
                bf16x8 bf = *reinterpret_cast<const bf16x8*>(W2T + (size_t)col * 128 + ks * 32 + quad * 8);
                #pragma unroll
                for (int rg = 0; rg < 4; ++rg)
                    acc2[rg] = __builtin_amdgcn_mfma_f32_16x16x32_bf16(a2[rg][ks], bf, acc2[rg], 0, 0, 0);
            }
            float bb = b2[col];
            int f = col & 127, cc = col >> 7;
            #pragma unroll
            for (int rg = 0; rg < 4; ++rg)
                #pragma unroll
                for (int r = 0; r < 4; ++r) {
                    int row = m0 + rg * 16 + quad * 4 + r;
                    if (row < N_NODES)
                        phi2[(size_t)row * 1024 + f * 8 + cc] = f2bf(acc2[rg][r] + bb);
                }
        }
        return;
    }

    bx -= PHI_BLOCKS;
    if (bx >= RC_BLOCKS) {
        // ---------------- pad: zero unused slots ----------------
        int t2 = (bx - RC_BLOCKS) * 256 + threadIdx.x;   // [0, 16N)
        int n = t2 >> 4, r = t2 & 15;
        int deg = cnt[n], tc = (deg + 15) >> 4;
        int p = deg + r;
        if (p < tc * 16) {
            size_t slot = (size_t)nb[n] + p;
            f32x4 z = {0.f, 0.f, 0.f, 0.f};
            f32x4* hp = reinterpret_cast<f32x4*>(hdr + slot * 16);
            hp[0] = z; hp[1] = z; hp[2] = z; hp[3] = z;
            f32x4* rp = reinterpret_cast<f32x4*>(Rc_s + slot * 32);
            rp[0] = z; rp[1] = z; rp[2] = z; rp[3] = z;
        }
        return;
    }

    // ---------------- rc: Rc + packed header at CSR slot ----------------
    int tid = bx * 256 + threadIdx.x;            // exactly E*8 threads
    int e = tid >> 3, sub = tid & 7;
    int lane = threadIdx.x & 63;
    float a = f1[e], b = f2[e], c = f3[e];
    int k0 = sub * 4;
    float4 r1 = *reinterpret_cast<const float4*>(R1 + (size_t)e * 32 + k0);
    float4 r2 = *reinterpret_cast<const float4*>(R2 + (size_t)e * 32 + k0);
    float4 r3 = *reinterpret_cast<const float4*>(R3 + (size_t)e * 32 + k0);
    ushort4 o;
    o.x = f2bf(r1.x * a + r2.x * b + r3.x * c);
    o.y = f2bf(r1.y * a + r2.y * b + r3.y * c);
    o.z = f2bf(r1.z * a + r2.z * b + r3.z * c);
    o.w = f2bf(r1.w * a + r2.w * b + r3.w * c);
    int slot = 0;
    if (sub == 0) slot = atomicAdd(&cursor[eix[e]], 1);
    slot = __shfl(slot, lane & 56);              // broadcast from sub0
    *reinterpret_cast<ushort4*>(Rc_s + (size_t)slot * 32 + k0) = o;
    if (sub == 0) {
        float4 h;
        h.x = __int_as_float(eix[N_EDGES + e]);  // j
        h.y = a + b + c;                         // fsum
        h.z = 0.f; h.w = 0.f;
        *reinterpret_cast<float4*>(hdr + (size_t)slot * 16) = h;
    } else if (sub < 4) {
        const float* up = (sub == 1 ? u1 : (sub == 2 ? u2 : u3)) + (size_t)e * 3;
        float4 h;
        h.x = up[0]; h.y = up[1]; h.z = up[2]; h.w = 0.f;
        *reinterpret_cast<float4*>(hdr + (size_t)slot * 16 + (size_t)sub * 4) = h;
    }
}

// ---------------------------------------------------------------------------
// Main msg kernel: round-0 pipeline shape (early coalesced header stage into
// double-buffered LDS, ONE barrier/tile) + round-1 slot-contiguous layout
// (no elist/eix/fsum/u* scatter, pad-zeroed rows -> branchless).
// ---------------------------------------------------------------------------
__global__ __launch_bounds__(512) void msg_kernel(
    const unsigned short* __restrict__ Rc_s, const float* __restrict__ hdr,
    const unsigned short* __restrict__ phi2, const unsigned short* __restrict__ vbf2,
    const unsigned short* __restrict__ WrT, const float* __restrict__ br,
    const int* __restrict__ tile_node, const int* __restrict__ ntiles,
    float* __restrict__ out0, float* __restrict__ out1)
{
    int t = threadIdx.x, lane = t & 63, w = t >> 6;
    int quad = lane >> 4, l16 = lane & 15;
    int fcol = w * 16 + l16;
    const int nt = *ntiles;

    bf16x8 bfrag[8];
    float brv[8];
    #pragma unroll
    for (int c = 0; c < 8; ++c) {
        int col = c * 128 + fcol;
        bfrag[c] = *reinterpret_cast<const bf16x8*>(WrT + (size_t)col * 32 + quad * 8);
        brv[c] = br[col];
    }

    __shared__ float srow[2][16][16];   // [j, fs, -, - | u1xyz,- | u2xyz,- | u3xyz,-]

    for (int t4 = 0; t4 < 4; ++t4) {
        int tile = blockIdx.x + t4 * MSG_GRID;
        if (tile >= nt) break;                   // uniform across block
        int node = tile_node[tile];
        size_t s0 = (size_t)tile * 16;
        int p = t4 & 1;

        // header stage: 256 threads, 1KB perfectly coalesced, issued EARLY
        if (t < 256) srow[p][t >> 4][t & 15] = hdr[s0 * 16 + t];

        // A-fragment: contiguous 1KB per tile (pad rows are zero)
        bf16x8 af = *reinterpret_cast<const bf16x8*>(Rc_s + (s0 + l16) * 32 + quad * 8);
        f32x4 acc[8];
        #pragma unroll
        for (int c = 0; c < 8; ++c) {
            f32x4 z = {0.f, 0.f, 0.f, 0.f};
            acc[c] = __builtin_amdgcn_mfma_f32_16x16x32_bf16(af, bfrag[c], z, 0, 0, 0);
        }

        __syncthreads();   // header visible; epilogue reads srow[p]

        float ds = 0.f, d0 = 0.f, d1 = 0.f, d2 = 0.f;
        #pragma unroll
        for (int r = 0; r < 4; ++r) {
            int row = quad * 4 + r;
            int j = __float_as_int(srow[p][row][0]);
            float fs = srow[p][row][1];
            size_t o = (size_t)j * 128 + fcol;
            u16x8 ph = *reinterpret_cast<const u16x8*>(phi2 + o * 8);
            ushort4 vb = *reinterpret_cast<const ushort4*>(vbf2 + o * 4);
            float x[8];
            #pragma unroll
            for (int c = 0; c < 8; ++c)
                x[c] = bf2f(ph[c]) * (acc[c][r] + brv[c] * fs);
            float vjx = bf2f(vb.x), vjy = bf2f(vb.y), vjz = bf2f(vb.z);
            float u1x = srow[p][row][4],  u1y = srow[p][row][5],  u1z = srow[p][row][6];
            float u2x = srow[p][row][8],  u2y = srow[p][row][9],  u2z = srow[p][row][10];
            float u3x = srow[p][row][12], u3y = srow[p][row][13], u3z = srow[p][row][14];
            // d += x1*vj + x2*u1 + x3*u2 + x4*u3 + vj x (x5*u1 + x6*u2 + x7*u3)
            float qx = x[5] * u1x + x[6] * u2x + x[7] * u3x;
            float qy = x[5] * u1y + x[6] * u2y + x[7] * u3y;
            float qz = x[5] * u1z + x[6] * u2z + x[7] * u3z;
            ds += x[0];
            d0 += x[1] * vjx + x[2] * u1x + x[3] * u2x + x[4] * u3x + vjy * qz - vjz * qy;
            d1 += x[1] * vjy + x[2] * u1y + x[3] * u2y + x[4] * u3y + vjz * qx - vjx * qz;
            d2 += x[1] * vjz + x[2] * u1z + x[3] * u2z + x[4] * u3z + vjx * qy - vjy * qx;
        }

        ds += __shfl_xor(ds, 16); ds += __shfl_xor(ds, 32);
        d0 += __shfl_xor(d0, 16); d0 += __shfl_xor(d0, 32);
        d1 += __shfl_xor(d1, 16); d1 += __shfl_xor(d1, 32);
        d2 += __shfl_xor(d2, 16); d2 += __shfl_xor(d2, 32);

        if (quad == 0) {
            atomicAdd(&out0[(size_t)node * 128 + fcol], ds);
            size_t vo = (size_t)node * 384 + fcol;
            atomicAdd(&out1[vo], d0);
            atomicAdd(&out1[vo + 128], d1);
            atomicAdd(&out1[vo + 256], d2);
        }
    }
}

// ---------------------------------------------------------------------------
extern "C" void kernel_launch(void* const* d_in, const int* in_sizes, int n_in,
                              void* d_out, int out_size, void* d_ws, size_t ws_size,
                              hipStream_t stream) {
    const float* s  = (const float*)d_in[0];
    const float* v  = (const float*)d_in[1];
    const float* R1 = (const float*)d_in[2];
    const float* R2 = (const float*)d_in[3];
    const float* R3 = (const float*)d_in[4];
    const float* f1 = (const float*)d_in[5];
    const float* f2 = (const float*)d_in[6];
    const float* f3 = (const float*)d_in[7];
    const float* u1 = (const float*)d_in[8];
    const float* u2 = (const float*)d_in[9];
    const float* u3 = (const float*)d_in[10];
    const int*  eix = (const int*)d_in[11];
    const float* W1 = (const float*)d_in[12];
    const float* b1 = (const float*)d_in[13];
    const float* W2 = (const float*)d_in[14];
    const float* b2 = (const float*)d_in[15];
    const float* Wr = (const float*)d_in[16];
    const float* br = (const float*)d_in[17];

    char* ws = (char*)d_ws;
    size_t off = 0;
    auto alloc = [&](size_t bytes) -> void* {
        void* p = ws + off;
        off = (off + bytes + 255) & ~(size_t)255;
        return p;
    };
    int* cnt       = (int*)alloc((size_t)N_NODES * 4);
    int* cursor    = (int*)alloc((size_t)N_NODES * 4);
    int* nb        = (int*)alloc((size_t)N_NODES * 4);
    int* tile_node = (int*)alloc((size_t)MAXT * 4);
    int* ntiles    = (int*)alloc(4);
    unsigned short* Rc_s = (unsigned short*)alloc((size_t)NSLOT * 32 * 2);
    float* hdr           = (float*)alloc((size_t)NSLOT * 16 * 4);
    unsigned short* vbf2 = (unsigned short*)alloc((size_t)N_NODES * 128 * 4 * 2);
    unsigned short* phi2 = (unsigned short*)alloc((size_t)N_NODES * 1024 * 2);
    unsigned short* W1T  = (unsigned short*)alloc(128 * 128 * 2);
    unsigned short* W2T  = (unsigned short*)alloc(1024 * 128 * 2);
    unsigned short* WrT  = (unsigned short*)alloc(1024 * 32 * 2);
    (void)ws_size; (void)in_sizes; (void)n_in; (void)out_size;

    float* out0 = (float*)d_out;
    float* out1 = out0 + (size_t)N_NODES * 128;

    hipMemsetAsync(cnt, 0, (size_t)N_NODES * 4, stream);
    init_kernel<<<5000, 256, 0, stream>>>(s, v, eix, W1, W2, Wr,
                                          out0, out1, vbf2, cnt, W1T, W2T, WrT);
    scan_kernel<<<1, 1024, 0, stream>>>(cnt, cursor, nb, tile_node, ntiles);
    rc_phi_kernel<<<PHI_BLOCKS + RC_BLOCKS + PAD_BLOCKS, 256, 0, stream>>>(
        R1, R2, R3, f1, f2, f3, u1, u2, u3, eix, cnt, nb, cursor, Rc_s, hdr,
        s, W1T, b1, W2T, b2, phi2);
    msg_kernel<<<MSG_GRID, 512, 0, stream>>>(Rc_s, hdr, phi2, vbf2, WrT, br,
                                             tile_node, ntiles, out0, out1);
}

// Round 5
// 321.844 us; speedup vs baseline: 1.3700x; 1.1194x over previous
//
#include <hip/hip_runtime.h>

#define N_NODES 10000
#define N_EDGES 160000
#define MAXT     19400              // >= sum(ceil(deg/16)) <= (E + 15N)/16 = 19375
#define NSLOT    (MAXT * 16 + 16)   // 16-aligned CSR slots + guard
#define MSG_GRID 5000               // x4 strided tiles = 20000 slots
#define PHI_BLOCKS 628
#define RC_BLOCKS 5000              // E*8 / 256
#define PAD_BLOCKS 625              // N*16 / 256

typedef __attribute__((ext_vector_type(8))) __bf16 bf16x8;
typedef __attribute__((ext_vector_type(8))) unsigned short u16x8;
typedef __attribute__((ext_vector_type(4))) float f32x4;

static __device__ __forceinline__ unsigned short f2bf(float x) {
    union { float f; unsigned u; } un;
    un.f = x;
    unsigned r = un.u + 0x7fffu + ((un.u >> 16) & 1u);  // RNE
    return (unsigned short)(r >> 16);
}

static __device__ __forceinline__ float bf2f(unsigned short h) {
    union { unsigned u; float f; } un;
    un.u = ((unsigned)h) << 16;
    return un.f;
}

// ---------------------------------------------------------------------------
// Fused init: float4 copies, weight transpose->bf16, vbf2 packing, degree
// histogram. Grid = 5000x256 = 1.28M threads (largest range).
// ---------------------------------------------------------------------------
__global__ __launch_bounds__(256) void init_kernel(
    const float* __restrict__ s, const float* __restrict__ v,
    const int* __restrict__ eix,
    const float* __restrict__ W1, const float* __restrict__ W2,
    const float* __restrict__ Wr,
    float* __restrict__ out0, float* __restrict__ out1,
    unsigned short* __restrict__ vbf2, int* __restrict__ cnt,
    unsigned short* __restrict__ W1T, unsigned short* __restrict__ W2T,
    unsigned short* __restrict__ WrT)
{
    int tid = blockIdx.x * 256 + threadIdx.x;
    if (tid < N_NODES * 96)                      // out1 = v, float4
        reinterpret_cast<float4*>(out1)[tid] = reinterpret_cast<const float4*>(v)[tid];
    if (tid < N_NODES * 32)                      // out0 = s, float4
        reinterpret_cast<float4*>(out0)[tid] = reinterpret_cast<const float4*>(s)[tid];
    if (tid < N_NODES * 128) {                   // vbf2[n][f] = {vx,vy,vz,0} bf16
        int n = tid >> 7, f = tid & 127;
        ushort4 q;
        q.x = f2bf(v[(size_t)n * 384 + f]);
        q.y = f2bf(v[(size_t)n * 384 + 128 + f]);
        q.z = f2bf(v[(size_t)n * 384 + 256 + f]);
        q.w = 0;
        *reinterpret_cast<ushort4*>(vbf2 + (size_t)tid * 4) = q;
    }
    if (tid < 131072) {                          // W2T [1024][128]
        int n = tid >> 7, k = tid & 127;
        W2T[tid] = f2bf(W2[k * 1024 + n]);
    }
    if (tid < 16384) {                           // W1T [128][128]
        int n = tid >> 7, k = tid & 127;
        W1T[tid] = f2bf(W1[k * 128 + n]);
    }
    if (tid < 32768) {                           // WrT [1024][32]
        int n = tid >> 5, k = tid & 31;
        WrT[tid] = f2bf(Wr[k * 1024 + n]);
    }
    if (tid < N_EDGES) atomicAdd(&cnt[eix[tid]], 1);
}

// ---------------------------------------------------------------------------
// Exclusive scan over tile counts; emits 16-aligned slot bases (nb/cursor in
// SLOT units) and the tile->node worklist.
// ---------------------------------------------------------------------------
__global__ __launch_bounds__(1024) void scan_kernel(
    const int* __restrict__ cnt, int* __restrict__ cursor,
    int* __restrict__ nb, int* __restrict__ tile_node,
    int* __restrict__ ntiles)
{
    __shared__ int ws[16];
    __shared__ int run_s;
    int t = threadIdx.x, lane = t & 63, wid = t >> 6;
    if (t == 0) run_s = 0;
    __syncthreads();
    for (int base = 0; base < N_NODES; base += 1024) {
        int idx = base + t;
        int deg = (idx < N_NODES) ? cnt[idx] : 0;
        int tc = (deg + 15) >> 4;
        int x = tc;
        #pragma unroll
        for (int o = 1; o < 64; o <<= 1) {
            int y = __shfl_up(x, o);
            if (lane >= o) x += y;
        }
        if (lane == 63) ws[wid] = x;
        __syncthreads();
        if (wid == 0) {
            int wv = (lane < 16) ? ws[lane] : 0;
            #pragma unroll
            for (int o = 1; o < 16; o <<= 1) {
                int y = __shfl_up(wv, o);
                if (lane >= o) wv += y;
            }
            if (lane < 16) ws[lane] = wv;
        }
        __syncthreads();
        int wb = wid ? ws[wid - 1] : 0;
        int ex = run_s + wb + x - tc;            // exclusive scan, tile units
        if (idx < N_NODES) {
            nb[idx] = ex * 16;                    // immutable slot base
            cursor[idx] = ex * 16;                // working cursor for rc
            for (int k = 0; k < tc; ++k) tile_node[ex + k] = idx;
        }
        __syncthreads();
        if (t == 0) run_s += ws[15];
        __syncthreads();
    }
    if (t == 0) *ntiles = run_s;
}

// ---------------------------------------------------------------------------
// Fused rc + pad + phi (one launch -> memory-bound rc overlaps MFMA-bound phi).
//  blocks [0, PHI_BLOCKS):                 phi = silu(s@W1+b1)@W2+b2 -> phi2
//  blocks [PHI_BLOCKS, +RC_BLOCKS):        per-edge Rc/hdr at CSR slot
//  blocks [PHI_BLOCKS+RC_BLOCKS, +PAD):    zero pad slots
// ---------------------------------------------------------------------------
__global__ __launch_bounds__(256) void rc_phi_kernel(
    const float* __restrict__ R1, const float* __restrict__ R2,
    const float* __restrict__ R3,
    const float* __restrict__ f1, const float* __restrict__ f2,
    const float* __restrict__ f3,
    const float* __restrict__ u1, const float* __restrict__ u2,
    const float* __restrict__ u3,
    const int* __restrict__ eix, const int* __restrict__ cnt,
    const int* __restrict__ nb, int* __restrict__ cursor,
    unsigned short* __restrict__ Rc_s, float* __restrict__ hdr,
    const float* __restrict__ s, const unsigned short* __restrict__ W1T,
    const float* __restrict__ b1, const unsigned short* __restrict__ W2T,
    const float* __restrict__ b2, unsigned short* __restrict__ phi2)
{
    __shared__ unsigned short h_lds[64][136];
    int bx = blockIdx.x;

    if (bx < PHI_BLOCKS) {
        // ---------------- phi ----------------
        int t = threadIdx.x, lane = t & 63, w = t >> 6;
        int quad = lane >> 4, l16 = lane & 15;
        int m0 = (bx >> 2) * 64;
        int colg = bx & 3;

        int arow = m0 + w * 16 + l16;
        if (arow > N_NODES - 1) arow = N_NODES - 1;
        bf16x8 afr[4];
        #pragma unroll
        for (int ks = 0; ks < 4; ++ks) {
            const float* sp = s + (size_t)arow * 128 + ks * 32 + quad * 8;
            #pragma unroll
            for (int jj = 0; jj < 8; ++jj) afr[ks][jj] = (__bf16)sp[jj];
        }
        #pragma unroll
        for (int cg = 0; cg < 8; ++cg) {
            int col = cg * 16 + l16;
            f32x4 acc = {0.f, 0.f, 0.f, 0.f};
            #pragma unroll
            for (int ks = 0; ks < 4; ++ks) {
                bf16x8 bf = *reinterpret_cast<const bf16x8*>(W1T + (size_t)col * 128 + ks * 32 + quad * 8);
                acc = __builtin_amdgcn_mfma_f32_16x16x32_bf16(afr[ks], bf, acc, 0, 0, 0);
            }
            float bb = b1[col];
            #pragma unroll
            for (int r = 0; r < 4; ++r) {
                int row = w * 16 + quad * 4 + r;
                float val = acc[r] + bb;
                h_lds[row][col] = f2bf(val / (1.f + __expf(-val)));
            }
        }
        __syncthreads();

        bf16x8 a2[4][4];
        #pragma unroll
        for (int rg = 0; rg < 4; ++rg)
            #pragma unroll
            for (int ks = 0; ks < 4; ++ks)
                a2[rg][ks] = *reinterpret_cast<const bf16x8*>(&h_lds[rg * 16 + l16][ks * 32 + quad * 8]);
        #pragma unroll
        for (int i = 0; i < 4; ++i) {
            int col = colg * 256 + w * 64 + i * 16 + l16;
            f32x4 acc2[4] = {{0,0,0,0},{0,0,0,0},{0,0,0,0},{0,0,0,0}};
            #pragma unroll
            for (int ks = 0; ks < 4; ++ks) {
                bf16x8 bf = *reinterpret_cast<const bf16x8*>(W2T + (size_t)col * 128 + ks * 32 + quad * 8);
                #pragma unroll
                for (int rg = 0; rg < 4; ++rg)
                    acc2[rg] = __builtin_amdgcn_mfma_f32_16x16x32_bf16(a2[rg][ks], bf, acc2[rg], 0, 0, 0);
            }
            float bb = b2[col];
            int f = col & 127, cc = col >> 7;
            #pragma unroll
            for (int rg = 0; rg < 4; ++rg)
                #pragma unroll
                for (int r = 0; r < 4; ++r) {
                    int row = m0 + rg * 16 + quad * 4 + r;
                    if (row < N_NODES)
                        phi2[(size_t)row * 1024 + f * 8 + cc] = f2bf(acc2[rg][r] + bb);
                }
        }
        return;
    }

    bx -= PHI_BLOCKS;
    if (bx >= RC_BLOCKS) {
        // ---------------- pad: zero unused slots ----------------
        int t2 = (bx - RC_BLOCKS) * 256 + threadIdx.x;   // [0, 16N)
        int n = t2 >> 4, r = t2 & 15;
        int deg = cnt[n], tc = (deg + 15) >> 4;
        int p = deg + r;
        if (p < tc * 16) {
            size_t slot = (size_t)nb[n] + p;
            f32x4 z = {0.f, 0.f, 0.f, 0.f};
            f32x4* hp = reinterpret_cast<f32x4*>(hdr + slot * 16);
            hp[0] = z; hp[1] = z; hp[2] = z; hp[3] = z;
            f32x4* rp = reinterpret_cast<f32x4*>(Rc_s + slot * 32);
            rp[0] = z; rp[1] = z; rp[2] = z; rp[3] = z;
        }
        return;
    }

    // ---------------- rc: Rc + packed header at CSR slot ----------------
    int tid = bx * 256 + threadIdx.x;            // exactly E*8 threads
    int e = tid >> 3, sub = tid & 7;
    int lane = threadIdx.x & 63;
    float a = f1[e], b = f2[e], c = f3[e];
    int k0 = sub * 4;
    float4 r1 = *reinterpret_cast<const float4*>(R1 + (size_t)e * 32 + k0);
    float4 r2 = *reinterpret_cast<const float4*>(R2 + (size_t)e * 32 + k0);
    float4 r3 = *reinterpret_cast<const float4*>(R3 + (size_t)e * 32 + k0);
    ushort4 o;
    o.x = f2bf(r1.x * a + r2.x * b + r3.x * c);
    o.y = f2bf(r1.y * a + r2.y * b + r3.y * c);
    o.z = f2bf(r1.z * a + r2.z * b + r3.z * c);
    o.w = f2bf(r1.w * a + r2.w * b + r3.w * c);
    int slot = 0;
    if (sub == 0) slot = atomicAdd(&cursor[eix[e]], 1);
    slot = __shfl(slot, lane & 56);              // broadcast from sub0
    *reinterpret_cast<ushort4*>(Rc_s + (size_t)slot * 32 + k0) = o;
    if (sub == 0) {
        float4 h;
        h.x = __int_as_float(eix[N_EDGES + e]);  // j
        h.y = a + b + c;                         // fsum
        h.z = 0.f; h.w = 0.f;
        *reinterpret_cast<float4*>(hdr + (size_t)slot * 16) = h;
    } else if (sub < 4) {
        const float* up = (sub == 1 ? u1 : (sub == 2 ? u2 : u3)) + (size_t)e * 3;
        float4 h;
        h.x = up[0]; h.y = up[1]; h.z = up[2]; h.w = 0.f;
        *reinterpret_cast<float4*>(hdr + (size_t)slot * 16 + (size_t)sub * 4) = h;
    }
}

// ---------------------------------------------------------------------------
// Main msg kernel: true double-buffer pipeline. Prologue stages tile k=0's
// header (coalesced 1KB) + A-fragment; each iteration stages tile k+1 AFTER
// the MFMAs so the header/A loads hide under the epilogue. One barrier/tile.
// srow stride 17 -> quads hit distinct banks. Epilogue is the r0 direct-cross
// form (measured 64 VGPR -> high occupancy on the unified VGPR/AGPR file).
// ---------------------------------------------------------------------------
__global__ __launch_bounds__(512) void msg_kernel(
    const unsigned short* __restrict__ Rc_s, const float* __restrict__ hdr,
    const unsigned short* __restrict__ phi2, const unsigned short* __restrict__ vbf2,
    const unsigned short* __restrict__ WrT, const float* __restrict__ br,
    const int* __restrict__ tile_node, const int* __restrict__ ntiles,
    float* __restrict__ out0, float* __restrict__ out1)
{
    int t = threadIdx.x, lane = t & 63, w = t >> 6;
    int quad = lane >> 4, l16 = lane & 15;
    int fcol = w * 16 + l16;
    const int nt = *ntiles;

    bf16x8 bfrag[8];
    float brv[8];
    #pragma unroll
    for (int c = 0; c < 8; ++c) {
        int col = c * 128 + fcol;
        bfrag[c] = *reinterpret_cast<const bf16x8*>(WrT + (size_t)col * 32 + quad * 8);
        brv[c] = br[col];
    }

    __shared__ float srow[2][16][17];   // [j, fs, -, - | u1xyz,- | u2xyz,- | u3xyz,-]

    int tile = blockIdx.x;
    bf16x8 af;
    if (tile < nt) {
        if (t < 256) srow[0][t >> 4][t & 15] = hdr[(size_t)tile * 256 + t];
        af = *reinterpret_cast<const bf16x8*>(Rc_s + ((size_t)tile * 16 + l16) * 32 + quad * 8);
    }

    for (int k = 0; tile < nt; ++k, tile += MSG_GRID) {
        int p = k & 1;
        __syncthreads();   // publishes srow[p]; reads of srow[p^1] all done

        f32x4 acc[8];
        #pragma unroll
        for (int c = 0; c < 8; ++c) {
            f32x4 z = {0.f, 0.f, 0.f, 0.f};
            acc[c] = __builtin_amdgcn_mfma_f32_16x16x32_bf16(af, bfrag[c], z, 0, 0, 0);
        }

        // stage NEXT tile (header -> srow[p^1], A-frag -> af) under the epilogue
        int tn = tile + MSG_GRID;
        if (tn < nt) {
            if (t < 256) srow[p ^ 1][t >> 4][t & 15] = hdr[(size_t)tn * 256 + t];
            af = *reinterpret_cast<const bf16x8*>(Rc_s + ((size_t)tn * 16 + l16) * 32 + quad * 8);
        }

        float ds = 0.f, d0 = 0.f, d1 = 0.f, d2 = 0.f;
        #pragma unroll
        for (int r = 0; r < 4; ++r) {
            int row = quad * 4 + r;
            int j = __float_as_int(srow[p][row][0]);
            float fs = srow[p][row][1];
            size_t o = (size_t)j * 128 + fcol;
            u16x8 ph = *reinterpret_cast<const u16x8*>(phi2 + o * 8);
            ushort4 vb = *reinterpret_cast<const ushort4*>(vbf2 + o * 4);
            float x[8];
            #pragma unroll
            for (int c = 0; c < 8; ++c)
                x[c] = bf2f(ph[c]) * (acc[c][r] + brv[c] * fs);
            float vjx = bf2f(vb.x), vjy = bf2f(vb.y), vjz = bf2f(vb.z);
            float u1x = srow[p][row][4],  u1y = srow[p][row][5],  u1z = srow[p][row][6];
            float u2x = srow[p][row][8],  u2y = srow[p][row][9],  u2z = srow[p][row][10];
            float u3x = srow[p][row][12], u3y = srow[p][row][13], u3z = srow[p][row][14];

            ds += x[0];
            d0 += vjx * x[1] + u1x * x[2] + u2x * x[3] + u3x * x[4]
                + x[5] * (vjy * u1z - vjz * u1y)
                + x[6] * (vjy * u2z - vjz * u2y)
                + x[7] * (vjy * u3z - vjz * u3y);
            d1 += vjy * x[1] + u1y * x[2] + u2y * x[3] + u3y * x[4]
                + x[5] * (vjz * u1x - vjx * u1z)
                + x[6] * (vjz * u2x - vjx * u2z)
                + x[7] * (vjz * u3x - vjx * u3z);
            d2 += vjz * x[1] + u1z * x[2] + u2z * x[3] + u3z * x[4]
                + x[5] * (vjx * u1y - vjy * u1x)
                + x[6] * (vjx * u2y - vjy * u2x)
                + x[7] * (vjx * u3y - vjy * u3x);
        }

        ds += __shfl_xor(ds, 16); ds += __shfl_xor(ds, 32);
        d0 += __shfl_xor(d0, 16); d0 += __shfl_xor(d0, 32);
        d1 += __shfl_xor(d1, 16); d1 += __shfl_xor(d1, 32);
        d2 += __shfl_xor(d2, 16); d2 += __shfl_xor(d2, 32);

        if (quad == 0) {
            int node = tile_node[tile];
            atomicAdd(&out0[(size_t)node * 128 + fcol], ds);
            size_t vo = (size_t)node * 384 + fcol;
            atomicAdd(&out1[vo], d0);
            atomicAdd(&out1[vo + 128], d1);
            atomicAdd(&out1[vo + 256], d2);
        }
    }
}

// ---------------------------------------------------------------------------
extern "C" void kernel_launch(void* const* d_in, const int* in_sizes, int n_in,
                              void* d_out, int out_size, void* d_ws, size_t ws_size,
                              hipStream_t stream) {
    const float* s  = (const float*)d_in[0];
    const float* v  = (const float*)d_in[1];
    const float* R1 = (const float*)d_in[2];
    const float* R2 = (const float*)d_in[3];
    const float* R3 = (const float*)d_in[4];
    const float* f1 = (const float*)d_in[5];
    const float* f2 = (const float*)d_in[6];
    const float* f3 = (const float*)d_in[7];
    const float* u1 = (const float*)d_in[8];
    const float* u2 = (const float*)d_in[9];
    const float* u3 = (const float*)d_in[10];
    const int*  eix = (const int*)d_in[11];
    const float* W1 = (const float*)d_in[12];
    const float* b1 = (const float*)d_in[13];
    const float* W2 = (const float*)d_in[14];
    const float* b2 = (const float*)d_in[15];
    const float* Wr = (const float*)d_in[16];
    const float* br = (const float*)d_in[17];

    char* ws = (char*)d_ws;
    size_t off = 0;
    auto alloc = [&](size_t bytes) -> void* {
        void* p = ws + off;
        off = (off + bytes + 255) & ~(size_t)255;
        return p;
    };
    int* cnt       = (int*)alloc((size_t)N_NODES * 4);
    int* cursor    = (int*)alloc((size_t)N_NODES * 4);
    int* nb        = (int*)alloc((size_t)N_NODES * 4);
    int* tile_node = (int*)alloc((size_t)MAXT * 4);
    int* ntiles    = (int*)alloc(4);
    unsigned short* Rc_s = (unsigned short*)alloc((size_t)NSLOT * 32 * 2);
    float* hdr           = (float*)alloc((size_t)NSLOT * 16 * 4);
    unsigned short* vbf2 = (unsigned short*)alloc((size_t)N_NODES * 128 * 4 * 2);
    unsigned short* phi2 = (unsigned short*)alloc((size_t)N_NODES * 1024 * 2);
    unsigned short* W1T  = (unsigned short*)alloc(128 * 128 * 2);
    unsigned short* W2T  = (unsigned short*)alloc(1024 * 128 * 2);
    unsigned short* WrT  = (unsigned short*)alloc(1024 * 32 * 2);
    (void)ws_size; (void)in_sizes; (void)n_in; (void)out_size;

    float* out0 = (float*)d_out;
    float* out1 = out0 + (size_t)N_NODES * 128;

    hipMemsetAsync(cnt, 0, (size_t)N_NODES * 4, stream);
    init_kernel<<<5000, 256, 0, stream>>>(s, v, eix, W1, W2, Wr,
                                          out0, out1, vbf2, cnt, W1T, W2T, WrT);
    scan_kernel<<<1, 1024, 0, stream>>>(cnt, cursor, nb, tile_node, ntiles);
    rc_phi_kernel<<<PHI_BLOCKS + RC_BLOCKS + PAD_BLOCKS, 256, 0, stream>>>(
        R1, R2, R3, f1, f2, f3, u1, u2, u3, eix, cnt, nb, cursor, Rc_s, hdr,
        s, W1T, b1, W2T, b2, phi2);
    msg_kernel<<<MSG_GRID, 512, 0, stream>>>(Rc_s, hdr, phi2, vbf2, WrT, br,
                                             tile_node, ntiles, out0, out1);
}

// Round 6
// 320.044 us; speedup vs baseline: 1.3777x; 1.0056x over previous
//
#include <hip/hip_runtime.h>

#define N_NODES 10000
#define N_EDGES 160000
#define MAXT     19400              // >= sum(ceil(deg/16)) <= (E + 15N)/16 = 19375
#define NSLOT    (MAXT * 16 + 16)   // 16-aligned CSR slots + guard
#define MSG_GRID 5000               // x4 strided tiles = 20000 slots
#define PHI_BLOCKS 628
#define RC_BLOCKS 5000              // E*8 / 256
#define PAD_BLOCKS 625              // N*16 / 256

typedef __attribute__((ext_vector_type(8))) __bf16 bf16x8;
typedef __attribute__((ext_vector_type(8))) unsigned short u16x8;
typedef __attribute__((ext_vector_type(4))) float f32x4;

static __device__ __forceinline__ unsigned short f2bf(float x) {
    union { float f; unsigned u; } un;
    un.f = x;
    unsigned r = un.u + 0x7fffu + ((un.u >> 16) & 1u);  // RNE
    return (unsigned short)(r >> 16);
}

static __device__ __forceinline__ float bf2f(unsigned short h) {
    union { unsigned u; float f; } un;
    un.u = ((unsigned)h) << 16;
    return un.f;
}

// ---------------------------------------------------------------------------
// Fused init: float4 copies, weight transpose->bf16, vbf2 packing, degree
// histogram. Grid = 5000x256.
// ---------------------------------------------------------------------------
__global__ __launch_bounds__(256) void init_kernel(
    const float* __restrict__ s, const float* __restrict__ v,
    const int* __restrict__ eix,
    const float* __restrict__ W1, const float* __restrict__ W2,
    const float* __restrict__ Wr,
    float* __restrict__ out0, float* __restrict__ out1,
    unsigned short* __restrict__ vbf2, int* __restrict__ cnt,
    unsigned short* __restrict__ W1T, unsigned short* __restrict__ W2T,
    unsigned short* __restrict__ WrT)
{
    int tid = blockIdx.x * 256 + threadIdx.x;
    if (tid < N_NODES * 96)                      // out1 = v, float4
        reinterpret_cast<float4*>(out1)[tid] = reinterpret_cast<const float4*>(v)[tid];
    if (tid < N_NODES * 32)                      // out0 = s, float4
        reinterpret_cast<float4*>(out0)[tid] = reinterpret_cast<const float4*>(s)[tid];
    if (tid < N_NODES * 128) {                   // vbf2[n][f] = {vx,vy,vz,0} bf16
        int n = tid >> 7, f = tid & 127;
        ushort4 q;
        q.x = f2bf(v[(size_t)n * 384 + f]);
        q.y = f2bf(v[(size_t)n * 384 + 128 + f]);
        q.z = f2bf(v[(size_t)n * 384 + 256 + f]);
        q.w = 0;
        *reinterpret_cast<ushort4*>(vbf2 + (size_t)tid * 4) = q;
    }
    if (tid < 131072) {                          // W2T [1024][128]
        int n = tid >> 7, k = tid & 127;
        W2T[tid] = f2bf(W2[k * 1024 + n]);
    }
    if (tid < 16384) {                           // W1T [128][128]
        int n = tid >> 7, k = tid & 127;
        W1T[tid] = f2bf(W1[k * 128 + n]);
    }
    if (tid < 32768) {                           // WrT [1024][32]
        int n = tid >> 5, k = tid & 31;
        WrT[tid] = f2bf(Wr[k * 1024 + n]);
    }
    if (tid < N_EDGES) atomicAdd(&cnt[eix[tid]], 1);
}

// ---------------------------------------------------------------------------
// Fused scan + phi. Blocks [0, PHI_BLOCKS) = phi (independent of scan);
// block PHI_BLOCKS = single-block scan (40 nodes/thread, one shfl pass) that
// hides entirely under phi. One launch instead of serial scan -> phi.
// ---------------------------------------------------------------------------
__global__ __launch_bounds__(256) void scan_phi_kernel(
    const int* __restrict__ cnt, int* __restrict__ cursor,
    int* __restrict__ nb, int* __restrict__ tile_node,
    int* __restrict__ ntiles,
    const float* __restrict__ s, const unsigned short* __restrict__ W1T,
    const float* __restrict__ b1, const unsigned short* __restrict__ W2T,
    const float* __restrict__ b2, unsigned short* __restrict__ phi2)
{
    __shared__ unsigned short h_lds[64][136];
    __shared__ int ws4[4];
    int bx = blockIdx.x;
    int t = threadIdx.x, lane = t & 63, w = t >> 6;

    if (bx == PHI_BLOCKS) {
        // ---------------- scan: 256 threads x 40 nodes ----------------
        int n0 = t * 40;
        int sum = 0;
        for (int i = 0; i < 40; ++i) {
            int n = n0 + i;
            if (n < N_NODES) sum += (cnt[n] + 15) >> 4;
        }
        int x = sum;
        #pragma unroll
        for (int o = 1; o < 64; o <<= 1) {
            int y = __shfl_up(x, o);
            if (lane >= o) x += y;
        }
        if (lane == 63) ws4[w] = x;
        __syncthreads();
        if (t < 4) {
            int v = ws4[t];
            #pragma unroll
            for (int o = 1; o < 4; o <<= 1) {
                int y = __shfl_up(v, o);
                if (lane >= o) v += y;
            }
            ws4[t] = v;                  // inclusive wave sums
        }
        __syncthreads();
        int wb = w ? ws4[w - 1] : 0;
        int run = wb + x - sum;          // exclusive prefix, tile units
        for (int i = 0; i < 40; ++i) {
            int n = n0 + i;
            if (n >= N_NODES) break;
            int tc = (cnt[n] + 15) >> 4;
            nb[n] = run * 16;
            cursor[n] = run * 16;
            for (int k = 0; k < tc; ++k) tile_node[run + k] = n;
            run += tc;
        }
        if (t == 255) *ntiles = run;
        return;
    }

    // ---------------- phi: silu(s@W1+b1)@W2+b2 ----------------
    int quad = lane >> 4, l16 = lane & 15;
    int m0 = (bx >> 2) * 64;
    int colg = bx & 3;

    int arow = m0 + w * 16 + l16;
    if (arow > N_NODES - 1) arow = N_NODES - 1;
    bf16x8 afr[4];
    #pragma unroll
    for (int ks = 0; ks < 4; ++ks) {
        const float* sp = s + (size_t)arow * 128 + ks * 32 + quad * 8;
        #pragma unroll
        for (int jj = 0; jj < 8; ++jj) afr[ks][jj] = (__bf16)sp[jj];
    }
    #pragma unroll
    for (int cg = 0; cg < 8; ++cg) {
        int col = cg * 16 + l16;
        f32x4 acc = {0.f, 0.f, 0.f, 0.f};
        #pragma unroll
        for (int ks = 0; ks < 4; ++ks) {
            bf16x8 bf = *reinterpret_cast<const bf16x8*>(W1T + (size_t)col * 128 + ks * 32 + quad * 8);
            acc = __builtin_amdgcn_mfma_f32_16x16x32_bf16(afr[ks], bf, acc, 0, 0, 0);
        }
        float bb = b1[col];
        #pragma unroll
        for (int r = 0; r < 4; ++r) {
            int row = w * 16 + quad * 4 + r;
            float val = acc[r] + bb;
            h_lds[row][col] = f2bf(val / (1.f + __expf(-val)));
        }
    }
    __syncthreads();

    bf16x8 a2[4][4];
    #pragma unroll
    for (int rg = 0; rg < 4; ++rg)
        #pragma unroll
        for (int ks = 0; ks < 4; ++ks)
            a2[rg][ks] = *reinterpret_cast<const bf16x8*>(&h_lds[rg * 16 + l16][ks * 32 + quad * 8]);
    #pragma unroll
    for (int i = 0; i < 4; ++i) {
        int col = colg * 256 + w * 64 + i * 16 + l16;
        f32x4 acc2[4] = {{0,0,0,0},{0,0,0,0},{0,0,0,0},{0,0,0,0}};
        #pragma unroll
        for (int ks = 0; ks < 4; ++ks) {
            bf16x8 bf = *reinterpret_cast<const bf16x8*>(W2T + (size_t)col * 128 + ks * 32 + quad * 8);
            #pragma unroll
            for (int rg = 0; rg < 4; ++rg)
                acc2[rg] = __builtin_amdgcn_mfma_f32_16x16x32_bf16(a2[rg][ks], bf, acc2[rg], 0, 0, 0);
        }
        float bb = b2[col];
        int f = col & 127, cc = col >> 7;
        #pragma unroll
        for (int rg = 0; rg < 4; ++rg)
            #pragma unroll
            for (int r = 0; r < 4; ++r) {
                int row = m0 + rg * 16 + quad * 4 + r;
                if (row < N_NODES)
                    phi2[(size_t)row * 1024 + f * 8 + cc] = f2bf(acc2[rg][r] + bb);
            }
    }
}

// ---------------------------------------------------------------------------
// rc + pad on the 128-B interleaved record: rec[slot] = {Rc 32xushort | hdr
// 16xfloat}. Per edge ONE contiguous 128B line (vs two scattered 64B halves).
//  blocks [0, RC_BLOCKS):      per-edge Rc/hdr at CSR slot
//  blocks [RC_BLOCKS, +PAD):   zero pad slots
// ---------------------------------------------------------------------------
__global__ __launch_bounds__(256) void rc_pad_kernel(
    const float* __restrict__ R1, const float* __restrict__ R2,
    const float* __restrict__ R3,
    const float* __restrict__ f1, const float* __restrict__ f2,
    const float* __restrict__ f3,
    const float* __restrict__ u1, const float* __restrict__ u2,
    const float* __restrict__ u3,
    const int* __restrict__ eix, const int* __restrict__ cnt,
    const int* __restrict__ nb, int* __restrict__ cursor,
    char* __restrict__ rec)
{
    int bx = blockIdx.x;
    if (bx >= RC_BLOCKS) {
        // ---------------- pad: zero unused slots (full 128B record) -------
        int t2 = (bx - RC_BLOCKS) * 256 + threadIdx.x;   // [0, 16N)
        int n = t2 >> 4, r = t2 & 15;
        int deg = cnt[n], tc = (deg + 15) >> 4;
        int p = deg + r;
        if (p < tc * 16) {
            size_t slot = (size_t)nb[n] + p;
            f32x4 z = {0.f, 0.f, 0.f, 0.f};
            f32x4* rp = reinterpret_cast<f32x4*>(rec + slot * 128);
            #pragma unroll
            for (int q = 0; q < 8; ++q) rp[q] = z;
        }
        return;
    }

    // ---------------- rc: Rc + packed header at CSR slot ----------------
    int tid = bx * 256 + threadIdx.x;            // exactly E*8 threads
    int e = tid >> 3, sub = tid & 7;
    int lane = threadIdx.x & 63;
    float a = f1[e], b = f2[e], c = f3[e];
    int k0 = sub * 4;
    float4 r1 = *reinterpret_cast<const float4*>(R1 + (size_t)e * 32 + k0);
    float4 r2 = *reinterpret_cast<const float4*>(R2 + (size_t)e * 32 + k0);
    float4 r3 = *reinterpret_cast<const float4*>(R3 + (size_t)e * 32 + k0);
    ushort4 o;
    o.x = f2bf(r1.x * a + r2.x * b + r3.x * c);
    o.y = f2bf(r1.y * a + r2.y * b + r3.y * c);
    o.z = f2bf(r1.z * a + r2.z * b + r3.z * c);
    o.w = f2bf(r1.w * a + r2.w * b + r3.w * c);
    int slot = 0;
    if (sub == 0) slot = atomicAdd(&cursor[eix[e]], 1);
    slot = __shfl(slot, lane & 56);              // broadcast from sub0
    *reinterpret_cast<ushort4*>(rec + (size_t)slot * 128 + k0 * 2) = o;
    float* hf = reinterpret_cast<float*>(rec + (size_t)slot * 128 + 64);
    if (sub == 0) {
        float4 h;
        h.x = __int_as_float(eix[N_EDGES + e]);  // j
        h.y = a + b + c;                         // fsum
        h.z = 0.f; h.w = 0.f;
        *reinterpret_cast<float4*>(hf) = h;
    } else if (sub < 4) {
        const float* up = (sub == 1 ? u1 : (sub == 2 ? u2 : u3)) + (size_t)e * 3;
        float4 h;
        h.x = up[0]; h.y = up[1]; h.z = up[2]; h.w = 0.f;
        *reinterpret_cast<float4*>(hf + sub * 4) = h;
    }
}

// ---------------------------------------------------------------------------
// Main msg kernel: double-buffer pipeline on the 128B record (tile = one
// contiguous 2KB block). srow stride 20 (16B-aligned rows) -> epilogue reads
// 1x ds_read_b64 + 3x ds_read_b128 per row instead of 11 scalars.
// ---------------------------------------------------------------------------
__global__ __launch_bounds__(512) void msg_kernel(
    const char* __restrict__ rec,
    const unsigned short* __restrict__ phi2, const unsigned short* __restrict__ vbf2,
    const unsigned short* __restrict__ WrT, const float* __restrict__ br,
    const int* __restrict__ tile_node, const int* __restrict__ ntiles,
    float* __restrict__ out0, float* __restrict__ out1)
{
    int t = threadIdx.x, lane = t & 63, w = t >> 6;
    int quad = lane >> 4, l16 = lane & 15;
    int fcol = w * 16 + l16;
    const int nt = *ntiles;
    const float* recf = reinterpret_cast<const float*>(rec);

    bf16x8 bfrag[8];
    float brv[8];
    #pragma unroll
    for (int c = 0; c < 8; ++c) {
        int col = c * 128 + fcol;
        bfrag[c] = *reinterpret_cast<const bf16x8*>(WrT + (size_t)col * 32 + quad * 8);
        brv[c] = br[col];
    }

    __shared__ __align__(16) float srow[2][16][20];  // [j,fs,-,-|u1 -,|u2 -,|u3 -,pad4]

    int tile = blockIdx.x;
    bf16x8 af;
    if (tile < nt) {
        if (t < 256)
            srow[0][t >> 4][t & 15] = recf[((size_t)tile * 16 + (t >> 4)) * 32 + 16 + (t & 15)];
        af = *reinterpret_cast<const bf16x8*>(rec + ((size_t)tile * 16 + l16) * 128 + quad * 16);
    }

    for (int k = 0; tile < nt; ++k, tile += MSG_GRID) {
        int p = k & 1;
        __syncthreads();   // publishes srow[p]; reads of srow[p^1] all done

        f32x4 acc[8];
        #pragma unroll
        for (int c = 0; c < 8; ++c) {
            f32x4 z = {0.f, 0.f, 0.f, 0.f};
            acc[c] = __builtin_amdgcn_mfma_f32_16x16x32_bf16(af, bfrag[c], z, 0, 0, 0);
        }

        // stage NEXT tile (header -> srow[p^1], A-frag -> af) under the epilogue
        int tn = tile + MSG_GRID;
        if (tn < nt) {
            if (t < 256)
                srow[p ^ 1][t >> 4][t & 15] = recf[((size_t)tn * 16 + (t >> 4)) * 32 + 16 + (t & 15)];
            af = *reinterpret_cast<const bf16x8*>(rec + ((size_t)tn * 16 + l16) * 128 + quad * 16);
        }

        float ds = 0.f, d0 = 0.f, d1 = 0.f, d2 = 0.f;
        #pragma unroll
        for (int r = 0; r < 4; ++r) {
            const float* rw = srow[p][quad * 4 + r];
            float2 jf = *reinterpret_cast<const float2*>(rw);
            f32x4 U1 = *reinterpret_cast<const f32x4*>(rw + 4);
            f32x4 U2 = *reinterpret_cast<const f32x4*>(rw + 8);
            f32x4 U3 = *reinterpret_cast<const f32x4*>(rw + 12);
            int j = __float_as_int(jf.x);
            float fs = jf.y;
            size_t o = (size_t)j * 128 + fcol;
            u16x8 ph = *reinterpret_cast<const u16x8*>(phi2 + o * 8);
            ushort4 vb = *reinterpret_cast<const ushort4*>(vbf2 + o * 4);
            float x[8];
            #pragma unroll
            for (int c = 0; c < 8; ++c)
                x[c] = bf2f(ph[c]) * (acc[c][r] + brv[c] * fs);
            float vjx = bf2f(vb.x), vjy = bf2f(vb.y), vjz = bf2f(vb.z);

            ds += x[0];
            d0 += vjx * x[1] + U1.x * x[2] + U2.x * x[3] + U3.x * x[4]
                + x[5] * (vjy * U1.z - vjz * U1.y)
                + x[6] * (vjy * U2.z - vjz * U2.y)
                + x[7] * (vjy * U3.z - vjz * U3.y);
            d1 += vjy * x[1] + U1.y * x[2] + U2.y * x[3] + U3.y * x[4]
                + x[5] * (vjz * U1.x - vjx * U1.z)
                + x[6] * (vjz * U2.x - vjx * U2.z)
                + x[7] * (vjz * U3.x - vjx * U3.z);
            d2 += vjz * x[1] + U1.z * x[2] + U2.z * x[3] + U3.z * x[4]
                + x[5] * (vjx * U1.y - vjy * U1.x)
                + x[6] * (vjx * U2.y - vjy * U2.x)
                + x[7] * (vjx * U3.y - vjy * U3.x);
        }

        ds += __shfl_xor(ds, 16); ds += __shfl_xor(ds, 32);
        d0 += __shfl_xor(d0, 16); d0 += __shfl_xor(d0, 32);
        d1 += __shfl_xor(d1, 16); d1 += __shfl_xor(d1, 32);
        d2 += __shfl_xor(d2, 16); d2 += __shfl_xor(d2, 32);

        if (quad == 0) {
            int node = tile_node[tile];
            atomicAdd(&out0[(size_t)node * 128 + fcol], ds);
            size_t vo = (size_t)node * 384 + fcol;
            atomicAdd(&out1[vo], d0);
            atomicAdd(&out1[vo + 128], d1);
            atomicAdd(&out1[vo + 256], d2);
        }
    }
}

// ---------------------------------------------------------------------------
extern "C" void kernel_launch(void* const* d_in, const int* in_sizes, int n_in,
                              void* d_out, int out_size, void* d_ws, size_t ws_size,
                              hipStream_t stream) {
    const float* s  = (const float*)d_in[0];
    const float* v  = (const float*)d_in[1];
    const float* R1 = (const float*)d_in[2];
    const float* R2 = (const float*)d_in[3];
    const float* R3 = (const float*)d_in[4];
    const float* f1 = (const float*)d_in[5];
    const float* f2 = (const float*)d_in[6];
    const float* f3 = (const float*)d_in[7];
    const float* u1 = (const float*)d_in[8];
    const float* u2 = (const float*)d_in[9];
    const float* u3 = (const float*)d_in[10];
    const int*  eix = (const int*)d_in[11];
    const float* W1 = (const float*)d_in[12];
    const float* b1 = (const float*)d_in[13];
    const float* W2 = (const float*)d_in[14];
    const float* b2 = (const float*)d_in[15];
    const float* Wr = (const float*)d_in[16];
    const float* br = (const float*)d_in[17];

    char* ws = (char*)d_ws;
    size_t off = 0;
    auto alloc = [&](size_t bytes) -> void* {
        void* p = ws + off;
        off = (off + bytes + 255) & ~(size_t)255;
        return p;
    };
    int* cnt       = (int*)alloc((size_t)N_NODES * 4);
    int* cursor    = (int*)alloc((size_t)N_NODES * 4);
    int* nb        = (int*)alloc((size_t)N_NODES * 4);
    int* tile_node = (int*)alloc((size_t)MAXT * 4);
    int* ntiles    = (int*)alloc(4);
    char* rec            = (char*)alloc((size_t)NSLOT * 128);
    unsigned short* vbf2 = (unsigned short*)alloc((size_t)N_NODES * 128 * 4 * 2);
    unsigned short* phi2 = (unsigned short*)alloc((size_t)N_NODES * 1024 * 2);
    unsigned short* W1T  = (unsigned short*)alloc(128 * 128 * 2);
    unsigned short* W2T  = (unsigned short*)alloc(1024 * 128 * 2);
    unsigned short* WrT  = (unsigned short*)alloc(1024 * 32 * 2);
    (void)ws_size; (void)in_sizes; (void)n_in; (void)out_size;

    float* out0 = (float*)d_out;
    float* out1 = out0 + (size_t)N_NODES * 128;

    hipMemsetAsync(cnt, 0, (size_t)N_NODES * 4, stream);
    init_kernel<<<5000, 256, 0, stream>>>(s, v, eix, W1, W2, Wr,
                                          out0, out1, vbf2, cnt, W1T, W2T, WrT);
    scan_phi_kernel<<<PHI_BLOCKS + 1, 256, 0, stream>>>(
        cnt, cursor, nb, tile_node, ntiles, s, W1T, b1, W2T, b2, phi2);
    rc_pad_kernel<<<RC_BLOCKS + PAD_BLOCKS, 256, 0, stream>>>(
        R1, R2, R3, f1, f2, f3, u1, u2, u3, eix, cnt, nb, cursor, rec);
    msg_kernel<<<MSG_GRID, 512, 0, stream>>>(rec, phi2, vbf2, WrT, br,
                                             tile_node, ntiles, out0, out1);
}